// Round 1
// 334.548 us; speedup vs baseline: 1.0941x; 1.0941x over previous
//
#include <hip/hip_runtime.h>
#include <stdint.h>

typedef __bf16 bf16;
typedef __bf16 bf16x4 __attribute__((ext_vector_type(4)));
typedef __bf16 bf16x8 __attribute__((ext_vector_type(8)));
typedef float  f32x4  __attribute__((ext_vector_type(4)));

#define MFMA16(a,b,c) __builtin_amdgcn_mfma_f32_16x16x32_bf16((a),(b),(c),0,0,0)

// Region A: x window [64][104] bf16 (13312 B), later v^T [96][64] XOR-swizzled (12288 B)
// Region B: q|k [64][200] (25600 B), later P [3][64][72] (27648 B), later O [64][104]
#define XS_STR 104
#define QK_STR 200
#define SB_STR 72
#define S_HEAD 4608   // 64*72 elements per head

// weight prep: fp32 [K][N] -> bf16 [N][K] (transposed) in workspace
__global__ void prep_weights(const float* __restrict__ qkv_w,
                             const float* __restrict__ proj_w,
                             bf16* __restrict__ wT) {
    int i = blockIdx.x * 256 + threadIdx.x;
    if (i < 288 * 96) {
        int j = i / 96, c = i - j * 96;
        wT[i] = (bf16)qkv_w[c * 288 + j];
    } else if (i < 288 * 96 + 96 * 96) {
        int t = i - 288 * 96;
        int j = t / 96, c = t - j * 96;
        wT[i] = (bf16)proj_w[c * 96 + j];
    }
}

__global__ __launch_bounds__(256, 4)
void win_attn_kernel(const float* __restrict__ x,
                     const float* __restrict__ qkv_b,
                     const float* __restrict__ proj_b,
                     const bf16* __restrict__ qkvwT,   // [288][96] bf16
                     const bf16* __restrict__ projwT,  // [96][96] bf16
                     float* __restrict__ out)
{
    __shared__ bf16 ldsA[64 * XS_STR];     // 13312 B
    __shared__ bf16 ldsB[3 * 64 * SB_STR]; // 27648 B

    const int tid  = threadIdx.x;
    const int wid  = tid >> 6;
    const int lane = tid & 63;
    const int lm   = lane & 15;   // row/col within 16-tile
    const int lq   = lane >> 4;   // quad 0..3

    const int wi = blockIdx.x;
    const int b  = wi >> 10;          // 1024 windows per batch image
    const int wr = wi & 1023;
    const int h0 = (wr >> 5) * 7;
    const int w0 = (wr & 31) * 7;

    // ---------------- Phase 0: stage x window -> bf16 LDS (region A) ----------------
    // 64 rows x 12 bf16x8-chunks = 768 slots = 3 x 256; rows >= 49 zero-filled.
    {
        const float* xbase = x + ((size_t)(b * 224 + h0) * 224 + w0) * 96;
        #pragma unroll
        for (int kk = 0; kk < 3; ++kk) {
            const int t   = tid + kk * 256;
            const int pix = t / 12;
            const int f8  = t - pix * 12;
            bf16x8 bv = {};
            if (pix < 49) {
                const int pr = pix / 7, pc = pix - pr * 7;
                const float* p = xbase + ((size_t)pr * 224 + pc) * 96 + f8 * 8;
                const float4 v0 = *(const float4*)p;
                const float4 v1 = *(const float4*)(p + 4);
                bv = (bf16x8){ (bf16)v0.x, (bf16)v0.y, (bf16)v0.z, (bf16)v0.w,
                               (bf16)v1.x, (bf16)v1.y, (bf16)v1.z, (bf16)v1.w };
            }
            *(bf16x8*)&ldsA[pix * XS_STR + f8 * 8] = bv;
        }
    }
    __syncthreads();   // b1: x staged

    // ---------------- Phase 1a: x B-fragments -> registers (lane lm = token) ----------------
    bf16x8 afr[4][3];
    #pragma unroll
    for (int tt = 0; tt < 4; ++tt)
        #pragma unroll
        for (int ks = 0; ks < 3; ++ks)
            afr[tt][ks] = *(const bf16x8*)&ldsA[(tt * 16 + lm) * XS_STR + ks * 32 + lq * 8];
    __syncthreads();   // b2: region A free -> v^T may be written

    // ---------------- Phase 1b: QKV GEMM ----------------
    // q,k tiles: SWAPPED mfma(W^T, x) -> feat-major C -> packed b64 stores into
    //   token-major [64][QK_STR] (reads downstream unchanged). Softmax scale folded into q.
    // v tiles: original orientation -> packed b64 stores into XOR-swizzled v^T [96][64].
    {
        const float Cs = 0.2550348607051632f;   // (1/sqrt(32)) * log2(e)
        for (int ft = wid; ft < 18; ft += 4) {
            bf16x8 wf[3];
            #pragma unroll
            for (int ks = 0; ks < 3; ++ks)
                wf[ks] = *(const bf16x8*)&qkvwT[(size_t)(ft * 16 + lm) * 96 + ks * 32 + lq * 8];
            if (ft < 12) {          // q (ft<6) or k (6<=ft<12), wave-uniform branch
                const f32x4 bias4 = *(const f32x4*)(qkv_b + ft * 16 + lq * 4);
                f32x4 acc[4];
                #pragma unroll
                for (int tt = 0; tt < 4; ++tt) acc[tt] = bias4;
                #pragma unroll
                for (int ks = 0; ks < 3; ++ks)
                    #pragma unroll
                    for (int tt = 0; tt < 4; ++tt)
                        acc[tt] = MFMA16(wf[ks], afr[tt][ks], acc[tt]);
                const bool isq = (ft < 6);
                #pragma unroll
                for (int tt = 0; tt < 4; ++tt) {
                    f32x4 a = acc[tt];
                    if (isq) a *= Cs;
                    bf16x4 pv = { (bf16)a[0], (bf16)a[1], (bf16)a[2], (bf16)a[3] };
                    *(bf16x4*)&ldsB[(tt * 16 + lm) * QK_STR + ft * 16 + lq * 4] = pv;
                }
            } else {                // v -> v^T[d][t], XOR-swizzled 8-elem groups
                const int d0 = (ft - 12) * 16 + lm;
                const float bias = qkv_b[192 + d0];
                f32x4 acc[4];
                #pragma unroll
                for (int mt = 0; mt < 4; ++mt) acc[mt] = (f32x4){bias, bias, bias, bias};
                #pragma unroll
                for (int ks = 0; ks < 3; ++ks)
                    #pragma unroll
                    for (int mt = 0; mt < 4; ++mt)
                        acc[mt] = MFMA16(afr[mt][ks], wf[ks], acc[mt]);
                #pragma unroll
                for (int mt = 0; mt < 4; ++mt) {
                    bf16x4 pv = { (bf16)acc[mt][0], (bf16)acc[mt][1],
                                  (bf16)acc[mt][2], (bf16)acc[mt][3] };
                    const int grp = mt * 2 + (lq >> 1);
                    *(bf16x4*)&ldsA[d0 * 64 + ((grp ^ (d0 & 7)) << 3) + ((lq & 1) << 2)] = pv;
                }
            }
        }
    }
    __syncthreads();   // b3: q,k,v^T ready

    // ---------------- Phase 2a: q,k fragments (lane lm = token, contiguous feats) ----------------
    bf16x8 aq[4], bk[4];
    if (wid < 3) {
        const int h = wid;
        #pragma unroll
        for (int qt = 0; qt < 4; ++qt)
            aq[qt] = *(const bf16x8*)&ldsB[(qt * 16 + lm) * QK_STR + h * 32 + lq * 8];
        #pragma unroll
        for (int kt = 0; kt < 4; ++kt)
            bk[kt] = *(const bf16x8*)&ldsB[(kt * 16 + lm) * QK_STR + 96 + h * 32 + lq * 8];
    }
    __syncthreads();   // b4: region B free -> P may be written

    // ---------------- Phase 2b: S^T = mfma(k,q); softmax (no max-pass, deferred norm); PV ----------------
    f32x4 oacc[2][4];
    f32x4 rin;
    if (wid < 3) {
        const int h = wid;
        const f32x4 zf = {0.f, 0.f, 0.f, 0.f};
        bf16* Sb = &ldsB[h * S_HEAD];
        f32x4 sums = zf;

        // per kt-tile: 4 MFMA -> exp2 -> packed b64 P stores (ktok on register axis,
        // pad-column masking is compile-time except (kt=3,i=0))
        #pragma unroll
        for (int kt = 0; kt < 4; ++kt) {
            f32x4 s[4];
            #pragma unroll
            for (int qt = 0; qt < 4; ++qt)
                s[qt] = MFMA16(bk[kt], aq[qt], zf);
            if (kt < 3) {
                #pragma unroll
                for (int qt = 0; qt < 4; ++qt) {
                    const float p0 = exp2f(s[qt][0]);
                    const float p1 = exp2f(s[qt][1]);
                    const float p2 = exp2f(s[qt][2]);
                    const float p3 = exp2f(s[qt][3]);
                    sums[qt] += (p0 + p1) + (p2 + p3);
                    bf16x4 pv = { (bf16)p0, (bf16)p1, (bf16)p2, (bf16)p3 };
                    *(bf16x4*)&Sb[(qt * 16 + lm) * SB_STR + kt * 16 + lq * 4] = pv;
                }
            } else {   // ktok = 48 + lq*4 + i: only (lq==0,i==0) valid
                #pragma unroll
                for (int qt = 0; qt < 4; ++qt) {
                    const float p0 = (lq == 0) ? exp2f(s[qt][0]) : 0.f;
                    sums[qt] += p0;
                    bf16x4 pv = { (bf16)p0, (bf16)0.f, (bf16)0.f, (bf16)0.f };
                    *(bf16x4*)&Sb[(qt * 16 + lm) * SB_STR + 48 + lq * 4] = pv;
                }
            }
        }
        // reduce row sums across the 4 quads, keep 1/sum in regs (deferred normalization)
        #pragma unroll
        for (int qt = 0; qt < 4; ++qt) {
            float sm = sums[qt];
            sm += __shfl_xor(sm, 16);
            sm += __shfl_xor(sm, 32);
            rin[qt] = __builtin_amdgcn_rcpf(sm);
        }
        asm volatile("s_waitcnt lgkmcnt(0)" ::: "memory");  // P stores visible to own-wave reads

        // PV swapped: O^T = mfma(v^T, P)  (M=32 feats, N=64 qtok, K=64 ktok)
        #pragma unroll
        for (int f2 = 0; f2 < 2; ++f2)
            #pragma unroll
            for (int qt = 0; qt < 4; ++qt) oacc[f2][qt] = zf;
        #pragma unroll
        for (int ks = 0; ks < 2; ++ks) {
            bf16x8 av[2], ap[4];
            #pragma unroll
            for (int f2 = 0; f2 < 2; ++f2) {
                const int frow = h * 32 + f2 * 16 + lm;
                av[f2] = *(const bf16x8*)&ldsA[frow * 64 + (((ks * 4 + lq) ^ (frow & 7)) << 3)];
            }
            #pragma unroll
            for (int qt = 0; qt < 4; ++qt)
                ap[qt] = *(const bf16x8*)&Sb[(qt * 16 + lm) * SB_STR + ks * 32 + lq * 8];
            #pragma unroll
            for (int f2 = 0; f2 < 2; ++f2)
                #pragma unroll
                for (int qt = 0; qt < 4; ++qt)
                    oacc[f2][qt] = MFMA16(av[f2], ap[qt], oacc[f2][qt]);
        }
        #pragma unroll
        for (int f2 = 0; f2 < 2; ++f2)
            #pragma unroll
            for (int qt = 0; qt < 4; ++qt)
                oacc[f2][qt] *= rin[qt];
    }
    __syncthreads();   // b5: all P reads done -> O may overwrite region B

    // ---------------- Phase 2c: write O (token-major [64][XS_STR]), packed b64 ----------------
    if (wid < 3) {
        const int h = wid;
        #pragma unroll
        for (int f2 = 0; f2 < 2; ++f2)
            #pragma unroll
            for (int qt = 0; qt < 4; ++qt) {
                const f32x4 a = oacc[f2][qt];
                bf16x4 ov = { (bf16)a[0], (bf16)a[1], (bf16)a[2], (bf16)a[3] };
                *(bf16x4*)&ldsB[(qt * 16 + lm) * XS_STR + h * 32 + f2 * 16 + lq * 4] = ov;
            }
    }
    __syncthreads();   // b6: O ready

    // ---------------- Phase 3: proj swapped: out^T-tiles = mfma(W^T, O); float4 stores ----------------
    {
        const int tt = wid;
        bf16x8 of[3];
        #pragma unroll
        for (int ks = 0; ks < 3; ++ks)
            of[ks] = *(const bf16x8*)&ldsB[(tt * 16 + lm) * XS_STR + ks * 32 + lq * 8];
        const int token = tt * 16 + lm;
        const int tv = (token < 49) ? token : 0;
        const int pr = tv / 7, pc = tv - pr * 7;
        float* obase = out + ((size_t)(b * 224 + h0 + pr) * 224 + (w0 + pc)) * 96 + lq * 4;
        #pragma unroll
        for (int ft = 0; ft < 6; ++ft) {
            bf16x8 wp[3];
            #pragma unroll
            for (int ks = 0; ks < 3; ++ks)
                wp[ks] = *(const bf16x8*)&projwT[(size_t)(ft * 16 + lm) * 96 + ks * 32 + lq * 8];
            f32x4 acc = *(const f32x4*)(proj_b + ft * 16 + lq * 4);
            #pragma unroll
            for (int ks = 0; ks < 3; ++ks)
                acc = MFMA16(wp[ks], of[ks], acc);
            if (token < 49)
                *(f32x4*)(obase + ft * 16) = acc;
        }
    }
}

extern "C" void kernel_launch(void* const* d_in, const int* in_sizes, int n_in,
                              void* d_out, int out_size, void* d_ws, size_t ws_size,
                              hipStream_t stream) {
    const float* x      = (const float*)d_in[0];
    const float* qkv_w  = (const float*)d_in[1];
    const float* qkv_b  = (const float*)d_in[2];
    const float* proj_w = (const float*)d_in[3];
    const float* proj_b = (const float*)d_in[4];
    float* out = (float*)d_out;

    bf16* wT = (bf16*)d_ws;                 // 288*96 + 96*96 bf16 = 73728 B
    const int n_w = 288 * 96 + 96 * 96;
    prep_weights<<<(n_w + 255) / 256, 256, 0, stream>>>(qkv_w, proj_w, wT);
    win_attn_kernel<<<8192, 256, 0, stream>>>(x, qkv_b, proj_b,
                                              wT, wT + 288 * 96, out);
}